// Round 23
// baseline (245.040 us; speedup 1.0000x reference)
//
#include <hip/hip_runtime.h>
#include <cstdint>

static constexpr float kEps  = 1e-5f;
static constexpr float kBeta = 0.1f;

typedef __attribute__((ext_vector_type(8))) short bf16x8;
typedef __attribute__((ext_vector_type(4))) float f32x4;

__device__ __forceinline__ ushort f2bf(float f){
  uint u = __float_as_uint(f);
  u += 0x7fff + ((u>>16)&1);      // round-to-nearest-even
  return (ushort)(u>>16);
}
__device__ __forceinline__ float bf2f(ushort h){
  return __uint_as_float(((uint)h)<<16);
}

// ---------------- CSR build ----------------
__global__ void k_hist(const int* __restrict__ row, int* __restrict__ deg, int E){
  int e = blockIdx.x*256 + threadIdx.x;
  if (e < E) atomicAdd(&deg[row[e]], 1);
}

__global__ void k_scan_block(const int* __restrict__ deg, int* __restrict__ start,
                             int* __restrict__ bsum, int N){
  __shared__ int s[256];
  int t = threadIdx.x;
  int i = blockIdx.x*256 + t;
  int v = (i < N) ? deg[i] : 0;
  s[t] = v; __syncthreads();
  for (int off=1; off<256; off<<=1){
    int add = (t >= off) ? s[t-off] : 0;
    __syncthreads();
    s[t] += add;
    __syncthreads();
  }
  if (i < N) start[i+1] = s[t];
  if (t == 255) bsum[blockIdx.x] = s[255];
}

__global__ void k_scan_bsum(const int* __restrict__ bsum, int* __restrict__ boff, int nb){
  __shared__ int s[256];
  int t = threadIdx.x;
  int v = (t < nb) ? bsum[t] : 0;
  s[t] = v; __syncthreads();
  for (int off=1; off<256; off<<=1){
    int add = (t >= off) ? s[t-off] : 0;
    __syncthreads();
    s[t] += add;
    __syncthreads();
  }
  if (t < nb) boff[t] = s[t] - v;   // exclusive
}

__global__ void k_scan_add(int* __restrict__ start, const int* __restrict__ boff, int N){
  int i = blockIdx.x*256 + threadIdx.x;
  if (i < N) start[i+1] += boff[blockIdx.x];
  if (blockIdx.x==0 && threadIdx.x==0) start[0] = 0;
}

__global__ void k_fill_bin(const int* __restrict__ row, const int* __restrict__ col,
                           const int* __restrict__ start, int* __restrict__ cursor,
                           int* __restrict__ colcsr, int E, int NR){
  const int p  = blockIdx.x & 7;
  const int q  = blockIdx.x >> 3;
  const int NQ = gridDim.x >> 3;
  const int lo = p*NR, hi = lo + NR;
  for (int e = q*256 + threadIdx.x; e < E; e += NQ*256){
    int r = row[e];
    if (r >= lo && r < hi){
      int pos = atomicAdd(&cursor[r], 1);
      colcsr[start[r] + pos] = col[e];
    }
  }
}

// ---------------- W1 -> bf16, k-chunk-contiguous layout ----------------
__global__ void k_prep_w1(const float* __restrict__ W1, ushort* __restrict__ W1s){
  int i = blockIdx.x*256 + threadIdx.x;   // i = k*256 + col
  int k = i >> 8, col = i & 255;
  W1s[(k>>5)*8192 + col*32 + (k&31)] = f2bf(W1[i]);
}

// ---- [256][64] fp32 weight -> bf16, layout [kc][col][kk] ----
__global__ void k_prep_w64(const float* __restrict__ W, ushort* __restrict__ Wh){
  int i = blockIdx.x*256 + threadIdx.x;   // i = k*64 + col, 16384 total
  int k = i >> 6, col = i & 63;
  Wh[(k>>5)*2048 + col*32 + (k&31)] = f2bf(W[i]);
}

// ---------------- GEMM1 (MFMA, bf16) + bias + relu + LN -> ego(bf16) ----
__global__ __launch_bounds__(256) void k_gemm1_mfma(const float* __restrict__ x,
    const ushort* __restrict__ W1s, const float* __restrict__ b1,
    const float* __restrict__ g, const float* __restrict__ bb,
    ushort* __restrict__ ego, int N){
  __shared__ ushort xh[64][40];
  __shared__ ushort wl[256][40];
  __shared__ float psum[64][4], psq[64][4];
  __shared__ float mub[64], ivb[64];

  const int tid = threadIdx.x;
  const int n0  = blockIdx.x*64;
  const int w   = tid>>6;
  const int l   = tid&63;
  const int l15 = l&15;
  const int lg  = l>>4;            // 0..3
  const int cb  = w*64;            // wave col base
  const int sxr = tid>>2;          // x row 0..63
  const int sxk = (tid&3)*8;       // k offset {0,8,16,24}

  f32x4 acc[4][4];
  #pragma unroll
  for (int rt=0;rt<4;rt++)
    #pragma unroll
    for (int ct=0;ct<4;ct++)
      acc[rt][ct] = (f32x4){0.f,0.f,0.f,0.f};

  for (int kc=0; kc<8; ++kc){
    if (kc) __syncthreads();
    const float* xp = &x[(size_t)min(n0+sxr, N-1)*256 + kc*32 + sxk];
    float4 v0 = *reinterpret_cast<const float4*>(xp);
    float4 v1 = *reinterpret_cast<const float4*>(xp+4);
    const float vv[8] = {v0.x,v0.y,v0.z,v0.w,v1.x,v1.y,v1.z,v1.w};
    bf16x8 hv;
    #pragma unroll
    for (int j=0;j<8;j++) hv[j] = (short)f2bf(vv[j]);
    *reinterpret_cast<bf16x8*>(&xh[sxr][sxk]) = hv;
    #pragma unroll
    for (int s2=0;s2<4;s2++){
      int rowi = (tid>>2) + s2*64;
      *reinterpret_cast<bf16x8*>(&wl[rowi][(tid&3)*8]) =
          *reinterpret_cast<const bf16x8*>(&W1s[kc*8192 + rowi*32 + (tid&3)*8]);
    }
    __syncthreads();
    bf16x8 ah[4];
    #pragma unroll
    for (int rt=0;rt<4;rt++)
      ah[rt] = *reinterpret_cast<const bf16x8*>(&xh[rt*16+l15][lg*8]);
    #pragma unroll
    for (int ct=0;ct<4;ct++){
      bf16x8 bv = *reinterpret_cast<const bf16x8*>(&wl[cb+ct*16+l15][lg*8]);
      #pragma unroll
      for (int rt=0;rt<4;rt++)
        acc[rt][ct] = __builtin_amdgcn_mfma_f32_16x16x32_bf16(ah[rt], bv, acc[rt][ct], 0,0,0);
    }
  }

  float b1v[4], gv[4], bbv[4];
  #pragma unroll
  for (int ct=0;ct<4;ct++){
    int col = cb + ct*16 + l15;
    b1v[ct] = b1[col]; gv[ct] = g[col]; bbv[ct] = bb[col];
  }
  #pragma unroll
  for (int rt=0;rt<4;rt++)
    #pragma unroll
    for (int ct=0;ct<4;ct++)
      #pragma unroll
      for (int r=0;r<4;r++)
        acc[rt][ct][r] = fmaxf(acc[rt][ct][r] + b1v[ct], 0.f);

  #pragma unroll
  for (int rt=0;rt<4;rt++){
    #pragma unroll
    for (int r=0;r<4;r++){
      float s = acc[rt][0][r]+acc[rt][1][r]+acc[rt][2][r]+acc[rt][3][r];
      float q = acc[rt][0][r]*acc[rt][0][r]+acc[rt][1][r]*acc[rt][1][r]
              + acc[rt][2][r]*acc[rt][2][r]+acc[rt][3][r]*acc[rt][3][r];
      #pragma unroll
      for (int o=1;o<16;o<<=1){ s += __shfl_xor(s,o); q += __shfl_xor(q,o); }
      if (l15 == 0){
        int row = rt*16 + lg*4 + r;
        psum[row][w] = s; psq[row][w] = q;
      }
    }
  }
  __syncthreads();
  if (tid < 64){
    float s = psum[tid][0]+psum[tid][1]+psum[tid][2]+psum[tid][3];
    float q = psq[tid][0]+psq[tid][1]+psq[tid][2]+psq[tid][3];
    float mu  = s * (1.f/256.f);
    float var = q * (1.f/256.f) - mu*mu;
    mub[tid] = mu;
    ivb[tid] = rsqrtf(fmaxf(var, 0.f) + kEps);
  }
  __syncthreads();
  #pragma unroll
  for (int rt=0;rt<4;rt++){
    #pragma unroll
    for (int r=0;r<4;r++){
      int row  = rt*16 + lg*4 + r;
      int grow = n0 + row;
      if (grow < N){
        float mu = mub[row], inv = ivb[row];
        size_t base = (size_t)grow*256 + cb + l15;
        #pragma unroll
        for (int ct=0;ct<4;ct++)
          ego[base + ct*16] = f2bf((acc[rt][ct][r]-mu)*inv*gv[ct] + bbv[ct]);
      }
    }
  }
}

// ------- MFMA 256->64 GEMM (bf16 x, bf16 W) -> bf16 h -------
__global__ __launch_bounds__(256) void k_hgemm_mfma(const ushort* __restrict__ x,
    const ushort* __restrict__ Wh, ushort* __restrict__ h, int N){
  __shared__ ushort xs[64][40];
  __shared__ ushort wh[64][40];
  const int tid = threadIdx.x;
  const int n0  = blockIdx.x*64;
  const int w   = tid>>6;
  const int l15 = tid&15;
  const int lg  = (tid&63)>>4;
  const int sxr = tid>>2;
  const int sxk = (tid&3)*8;

  f32x4 acc[4];
  #pragma unroll
  for (int ct=0;ct<4;ct++) acc[ct] = (f32x4){0.f,0.f,0.f,0.f};

  for (int kc=0; kc<8; ++kc){
    if (kc) __syncthreads();
    *reinterpret_cast<bf16x8*>(&xs[sxr][sxk]) =
        *reinterpret_cast<const bf16x8*>(&x[(size_t)min(n0+sxr, N-1)*256 + kc*32 + sxk]);
    int src = kc*2048 + sxr*32 + sxk;
    *reinterpret_cast<bf16x8*>(&wh[sxr][sxk]) =
        *reinterpret_cast<const bf16x8*>(&Wh[src]);
    __syncthreads();
    bf16x8 ah = *reinterpret_cast<const bf16x8*>(&xs[w*16+l15][lg*8]);
    #pragma unroll
    for (int ct=0;ct<4;ct++){
      bf16x8 bh = *reinterpret_cast<const bf16x8*>(&wh[ct*16+l15][lg*8]);
      acc[ct] = __builtin_amdgcn_mfma_f32_16x16x32_bf16(ah, bh, acc[ct], 0,0,0);
    }
  }
  #pragma unroll
  for (int r=0;r<4;r++){
    int grow = n0 + w*16 + lg*4 + r;
    if (grow < N){
      #pragma unroll
      for (int ct=0;ct<4;ct++)
        h[(size_t)grow*64 + ct*16 + l15] = f2bf(acc[ct][r]);
    }
  }
}

// ------- MFMA 256->64 GEMM + bias + log_softmax -> out -------
__global__ __launch_bounds__(256) void k_out_mfma(const ushort* __restrict__ x,
    const ushort* __restrict__ Wh, const float* __restrict__ b2,
    float* __restrict__ out, int N){
  __shared__ ushort xs[64][40];
  __shared__ ushort wh[64][40];
  const int tid = threadIdx.x;
  const int n0  = blockIdx.x*64;
  const int w   = tid>>6;
  const int l15 = tid&15;
  const int lg  = (tid&63)>>4;
  const int sxr = tid>>2;
  const int sxk = (tid&3)*8;

  f32x4 acc[4];
  #pragma unroll
  for (int ct=0;ct<4;ct++) acc[ct] = (f32x4){0.f,0.f,0.f,0.f};

  for (int kc=0; kc<8; ++kc){
    if (kc) __syncthreads();
    *reinterpret_cast<bf16x8*>(&xs[sxr][sxk]) =
        *reinterpret_cast<const bf16x8*>(&x[(size_t)min(n0+sxr, N-1)*256 + kc*32 + sxk]);
    int src = kc*2048 + sxr*32 + sxk;
    *reinterpret_cast<bf16x8*>(&wh[sxr][sxk]) =
        *reinterpret_cast<const bf16x8*>(&Wh[src]);
    __syncthreads();
    bf16x8 ah = *reinterpret_cast<const bf16x8*>(&xs[w*16+l15][lg*8]);
    #pragma unroll
    for (int ct=0;ct<4;ct++){
      bf16x8 bh = *reinterpret_cast<const bf16x8*>(&wh[ct*16+l15][lg*8]);
      acc[ct] = __builtin_amdgcn_mfma_f32_16x16x32_bf16(ah, bh, acc[ct], 0,0,0);
    }
  }

  float b2v[4];
  #pragma unroll
  for (int ct=0;ct<4;ct++) b2v[ct] = b2[ct*16+l15];

  #pragma unroll
  for (int r=0;r<4;r++){
    float v[4];
    #pragma unroll
    for (int ct=0;ct<4;ct++) v[ct] = acc[ct][r] + b2v[ct];
    float mx = fmaxf(fmaxf(v[0],v[1]), fmaxf(v[2],v[3]));
    #pragma unroll
    for (int o=1;o<16;o<<=1) mx = fmaxf(mx, __shfl_xor(mx,o));
    float sm = __expf(v[0]-mx)+__expf(v[1]-mx)+__expf(v[2]-mx)+__expf(v[3]-mx);
    #pragma unroll
    for (int o=1;o<16;o<<=1) sm += __shfl_xor(sm,o);
    float ls = __logf(sm);
    int grow = n0 + w*16 + lg*4 + r;
    if (grow < N){
      #pragma unroll
      for (int ct=0;ct<4;ct++)
        out[(size_t)grow*64 + ct*16 + l15] = (v[ct]-mx) - ls;
    }
  }
}

// ------- FUSED edge phase, 2-wave blocks (8 nodes), LDS-staged h[row] -------
// Block = 128 threads, 8 nodes, 8 groups of 16 (group = node). Chunk = 128
// edges. Phase 1: thread=edge (~100% util), attention in-register, stash
// a + h[col] in LDS. Phase 2: group g accumulates node nb+g's slice.
__global__ __launch_bounds__(128) void k_att_agg(
    const ushort* __restrict__ h,      // [N][64] bf16
    const int* __restrict__ colcsr, const int* __restrict__ start,
    const float* __restrict__ attw,    // [64][4]
    const ushort* __restrict__ ego,    // [N][256] bf16
    const float* __restrict__ g, const float* __restrict__ b,
    ushort* __restrict__ xout, int N){
  __shared__ ushort s_hr[8][72];
  __shared__ ushort s_hc[128][72];
  __shared__ float4 s_a[128];
  __shared__ int    s_st[9];

  const int tid  = threadIdx.x;        // 0..127
  const int grp  = tid >> 4;           // 0..7  (group = node)
  const int l15  = tid & 15;
  const int nb   = blockIdx.x*8;
  const int n    = nb + grp;

  if (tid < 9) s_st[tid] = start[min(nb + tid, N)];

  // stage the block's 8 h[row] rows (group g loads its node's row)
  *reinterpret_cast<ushort4*>(&s_hr[grp][l15*4]) =
      *reinterpret_cast<const ushort4*>(&h[(size_t)min(n, N-1)*64 + l15*4]);
  __syncthreads();

  const int b0 = s_st[0];
  const int b1 = s_st[8];
  const int s0 = (n < N) ? s_st[grp]   : b1;
  const int s1 = (n < N) ? s_st[grp+1] : b1;

  float acc[4][4];   // [gate][dim j]
  #pragma unroll
  for (int c=0;c<4;c++)
    #pragma unroll
    for (int j=0;j<4;j++) acc[c][j]=0.f;

  for (int base = b0; base < b1; base += 128){
    const int cnt = min(b1 - base, 128);
    // ---- phase 1: one thread per edge; only h[col] from global ----
    if (tid < cnt){
      int edge = base + tid;
      int rl = 0;
      #pragma unroll
      for (int k=1;k<8;k++) rl += (edge >= s_st[k]) ? 1 : 0;
      int c = colcsr[edge];
      const uint4* hrp = reinterpret_cast<const uint4*>(&s_hr[rl][0]);
      const uint4* hcp = reinterpret_cast<const uint4*>(h + (size_t)c*64);
      float q0=0.f, q1=0.f, q2=0.f, q3=0.f;
      #pragma unroll
      for (int s=0; s<8; ++s){
        uint4 hr4 = hrp[s];
        uint4 hc4 = hcp[s];
        *reinterpret_cast<uint4*>(&s_hc[tid][s*8]) = hc4;
        const uint hru[4] = {hr4.x, hr4.y, hr4.z, hr4.w};
        const uint hcu[4] = {hc4.x, hc4.y, hc4.z, hc4.w};
        #pragma unroll
        for (int t=0; t<4; ++t){
          float hrl = __uint_as_float(hru[t]<<16);
          float hrh = __uint_as_float(hru[t]&0xffff0000u);
          float hcl = __uint_as_float(hcu[t]<<16);
          float hch = __uint_as_float(hcu[t]&0xffff0000u);
          float pl = fmaxf(fmaf(0.5f, hrl, hcl), 0.f);
          float ph = fmaxf(fmaf(0.5f, hrh, hch), 0.f);
          int d = s*8 + t*2;
          float4 w0 = *reinterpret_cast<const float4*>(&attw[(d  )*4]);  // uniform
          float4 w1 = *reinterpret_cast<const float4*>(&attw[(d+1)*4]);  // uniform
          q0 = fmaf(pl, w0.x, q0); q1 = fmaf(pl, w0.y, q1);
          q2 = fmaf(pl, w0.z, q2); q3 = fmaf(pl, w0.w, q3);
          q0 = fmaf(ph, w1.x, q0); q1 = fmaf(ph, w1.y, q1);
          q2 = fmaf(ph, w1.z, q2); q3 = fmaf(ph, w1.w, q3);
        }
      }
      float m = fmaxf(fmaxf(q0,q1), fmaxf(q2,q3));
      float e0=__expf(q0-m), e1=__expf(q1-m), e2=__expf(q2-m), e3=__expf(q3-m);
      float inv = 1.f/(e0+e1+e2+e3);
      s_a[tid] = make_float4(e0*inv, e1*inv, e2*inv, e3*inv);
    }
    __syncthreads();
    // ---- phase 2: group accumulates its node's slice from LDS ----
    int lo = max(s0, base), hi = min(s1, base + cnt);
    for (int i = lo; i < hi; ++i){
      int e = i - base;
      float4 av = s_a[e];
      ushort4 hv = *reinterpret_cast<const ushort4*>(&s_hc[e][l15*4]);
      float d0=bf2f(hv.x), d1=bf2f(hv.y), d2=bf2f(hv.z), d3=bf2f(hv.w);
      acc[0][0]=fmaf(av.x,d0,acc[0][0]); acc[0][1]=fmaf(av.x,d1,acc[0][1]);
      acc[0][2]=fmaf(av.x,d2,acc[0][2]); acc[0][3]=fmaf(av.x,d3,acc[0][3]);
      acc[1][0]=fmaf(av.y,d0,acc[1][0]); acc[1][1]=fmaf(av.y,d1,acc[1][1]);
      acc[1][2]=fmaf(av.y,d2,acc[1][2]); acc[1][3]=fmaf(av.y,d3,acc[1][3]);
      acc[2][0]=fmaf(av.z,d0,acc[2][0]); acc[2][1]=fmaf(av.z,d1,acc[2][1]);
      acc[2][2]=fmaf(av.z,d2,acc[2][2]); acc[2][3]=fmaf(av.z,d3,acc[2][3]);
      acc[3][0]=fmaf(av.w,d0,acc[3][0]); acc[3][1]=fmaf(av.w,d1,acc[3][1]);
      acc[3][2]=fmaf(av.w,d2,acc[3][2]); acc[3][3]=fmaf(av.w,d3,acc[3][3]);
    }
    if (base + 128 < b1) __syncthreads();   // block-uniform
  }

  if (n >= N) return;

  // ---- epilogue: relu + LN (in-group reduce) + blend; group owns 256 cols ----
  #pragma unroll
  for (int c=0;c<4;c++)
    #pragma unroll
    for (int j=0;j<4;j++)
      acc[c][j] = fmaxf(acc[c][j], 0.f);

  float s=0.f, sq=0.f;
  #pragma unroll
  for (int c=0;c<4;c++)
    #pragma unroll
    for (int j=0;j<4;j++){ float v=acc[c][j]; s+=v; sq+=v*v; }
  #pragma unroll
  for (int o=1;o<16;o<<=1){ s += __shfl_xor(s,o); sq += __shfl_xor(sq,o); }
  float mu  = s * (1.f/256.f);
  float var = sq * (1.f/256.f) - mu*mu;
  float inv = rsqrtf(fmaxf(var,0.f) + kEps);

  size_t nbase = (size_t)n*256;
  #pragma unroll
  for (int c=0;c<4;c++){
    int colb = c*64 + l15*4;
    float4 gv  = *reinterpret_cast<const float4*>(&g[colb]);
    float4 bv  = *reinterpret_cast<const float4*>(&b[colb]);
    ushort4 ev = *reinterpret_cast<const ushort4*>(&ego[nbase + colb]);
    ushort4 y;
    y.x = f2bf((1.f-kBeta)*((acc[c][0]-mu)*inv*gv.x + bv.x) + kBeta*bf2f(ev.x));
    y.y = f2bf((1.f-kBeta)*((acc[c][1]-mu)*inv*gv.y + bv.y) + kBeta*bf2f(ev.y));
    y.z = f2bf((1.f-kBeta)*((acc[c][2]-mu)*inv*gv.z + bv.z) + kBeta*bf2f(ev.z));
    y.w = f2bf((1.f-kBeta)*((acc[c][3]-mu)*inv*gv.w + bv.w) + kBeta*bf2f(ev.w));
    *reinterpret_cast<ushort4*>(&xout[nbase + colb]) = y;
  }
}

extern "C" void kernel_launch(void* const* d_in, const int* in_sizes, int n_in,
                              void* d_out, int out_size, void* d_ws, size_t ws_size,
                              hipStream_t stream){
  const float* x_in = (const float*)d_in[0];
  const int*   ei   = (const int*)d_in[1];
  const float* W1   = (const float*)d_in[2];
  const float* b1   = (const float*)d_in[3];
  const float* lin  = (const float*)d_in[4];
  const float* att  = (const float*)d_in[5];
  const float* lng  = (const float*)d_in[6];
  const float* lnb  = (const float*)d_in[7];
  const float* W2   = (const float*)d_in[8];
  const float* b2   = (const float*)d_in[9];
  float* out = (float*)d_out;

  const int N = in_sizes[0] / 256;   // 50000
  const int E = in_sizes[1] / 2;     // 800000
  const int* row = ei;
  const int* col = ei + E;

  char* basep = (char*)d_ws;
  size_t off = 0;
  auto alloc = [&](size_t bytes)->char*{
    char* p = basep + off;
    off += (bytes + 255) & ~(size_t)255;
    return p;
  };
  ushort* ego    = (ushort*)alloc((size_t)N*256*2);
  ushort* xbuf   = (ushort*)alloc((size_t)N*256*2);
  ushort* hbuf   = (ushort*)alloc((size_t)N*64*2);
  int*    startp = (int*)   alloc((size_t)(N+1)*4);
  int*    deg    = (int*)   alloc((size_t)N*4);   // also reused as cursor
  int*    colcsr = (int*)   alloc((size_t)E*4);
  int*    bsum   = (int*)   alloc(256*4);
  int*    boff   = (int*)   alloc(256*4);
  ushort* W1s    = (ushort*)alloc((size_t)256*256*2);
  ushort* linh   = (ushort*)alloc((size_t)2*16384*2);
  ushort* W2h    = (ushort*)alloc((size_t)16384*2);

  int nbE = (E + 255)/256;   // 3125
  int nbN = (N + 255)/256;   // 196
  int nbT = (N + 63)/64;     // 782 tiles
  int NR  = (N + 7)/8;       // node range per XCD class

  // CSR build (simple hist, binned fill)
  hipMemsetAsync(deg, 0, (size_t)N*4, stream);
  k_hist<<<nbE,256,0,stream>>>(row, deg, E);
  k_scan_block<<<nbN,256,0,stream>>>(deg, startp, bsum, N);
  k_scan_bsum<<<1,256,0,stream>>>(bsum, boff, nbN);
  k_scan_add<<<nbN,256,0,stream>>>(startp, boff, N);
  hipMemsetAsync(deg, 0, (size_t)N*4, stream);     // cursor
  k_fill_bin<<<1024,256,0,stream>>>(row, col, startp, deg, colcsr, E, NR);

  // weight prep
  k_prep_w1<<<256,256,0,stream>>>(W1, W1s);
  k_prep_w64<<<64,256,0,stream>>>(lin,          linh);
  k_prep_w64<<<64,256,0,stream>>>(lin + 16384,  linh + 16384);
  k_prep_w64<<<64,256,0,stream>>>(W2, W2h);

  // MFMA projection + bias + relu + LN -> ego (bf16)
  k_gemm1_mfma<<<nbT,256,0,stream>>>(x_in, W1s, b1, lng, lnb, ego, N);

  for (int L=0; L<2; ++L){
    const ushort* xsrc = (L == 0) ? ego : xbuf;
    k_hgemm_mfma<<<nbT,256,0,stream>>>(xsrc, linh + (size_t)L*16384, hbuf, N);
    k_att_agg<<<(N+7)/8,128,0,stream>>>(hbuf, colcsr, startp,
                                        att + (size_t)L*64*4, ego,
                                        lng + (size_t)(L+1)*256, lnb + (size_t)(L+1)*256,
                                        xbuf, N);
  }
  k_out_mfma<<<nbT,256,0,stream>>>(xbuf, W2h, b2, out, N);
}

// Round 24
// 242.113 us; speedup vs baseline: 1.0121x; 1.0121x over previous
//
#include <hip/hip_runtime.h>
#include <cstdint>

static constexpr float kEps  = 1e-5f;
static constexpr float kBeta = 0.1f;

typedef __attribute__((ext_vector_type(8))) short bf16x8;
typedef __attribute__((ext_vector_type(4))) float f32x4;

__device__ __forceinline__ ushort f2bf(float f){
  uint u = __float_as_uint(f);
  u += 0x7fff + ((u>>16)&1);      // round-to-nearest-even
  return (ushort)(u>>16);
}
__device__ __forceinline__ float bf2f(ushort h){
  return __uint_as_float(((uint)h)<<16);
}

// ---------------- CSR build ----------------
__global__ void k_hist(const int* __restrict__ row, int* __restrict__ deg, int E){
  int e = blockIdx.x*256 + threadIdx.x;
  if (e < E) atomicAdd(&deg[row[e]], 1);
}

__global__ void k_scan_block(const int* __restrict__ deg, int* __restrict__ start,
                             int* __restrict__ bsum, int N){
  __shared__ int s[256];
  int t = threadIdx.x;
  int i = blockIdx.x*256 + t;
  int v = (i < N) ? deg[i] : 0;
  s[t] = v; __syncthreads();
  for (int off=1; off<256; off<<=1){
    int add = (t >= off) ? s[t-off] : 0;
    __syncthreads();
    s[t] += add;
    __syncthreads();
  }
  if (i < N) start[i+1] = s[t];
  if (t == 255) bsum[blockIdx.x] = s[255];
}

__global__ void k_scan_bsum(const int* __restrict__ bsum, int* __restrict__ boff, int nb){
  __shared__ int s[256];
  int t = threadIdx.x;
  int v = (t < nb) ? bsum[t] : 0;
  s[t] = v; __syncthreads();
  for (int off=1; off<256; off<<=1){
    int add = (t >= off) ? s[t-off] : 0;
    __syncthreads();
    s[t] += add;
    __syncthreads();
  }
  if (t < nb) boff[t] = s[t] - v;   // exclusive
}

__global__ void k_scan_add(int* __restrict__ start, const int* __restrict__ boff, int N){
  int i = blockIdx.x*256 + threadIdx.x;
  if (i < N) start[i+1] += boff[blockIdx.x];
  if (blockIdx.x==0 && threadIdx.x==0) start[0] = 0;
}

// 4-class binned col scatter: class slice (~800KB) still L2-resident,
// read amplification halved vs 8 classes.
__global__ void k_fill_bin(const int* __restrict__ row, const int* __restrict__ col,
                           const int* __restrict__ start, int* __restrict__ cursor,
                           int* __restrict__ colcsr, int E, int NR){
  const int p  = blockIdx.x & 3;
  const int q  = blockIdx.x >> 2;
  const int NQ = gridDim.x >> 2;
  const int lo = p*NR, hi = lo + NR;
  for (int e = q*256 + threadIdx.x; e < E; e += NQ*256){
    int r = row[e];
    if (r >= lo && r < hi){
      int pos = atomicAdd(&cursor[r], 1);
      colcsr[start[r] + pos] = col[e];
    }
  }
}

// ---------------- W1 -> bf16, k-chunk-contiguous layout ----------------
__global__ void k_prep_w1(const float* __restrict__ W1, ushort* __restrict__ W1s){
  int i = blockIdx.x*256 + threadIdx.x;   // i = k*256 + col
  int k = i >> 8, col = i & 255;
  W1s[(k>>5)*8192 + col*32 + (k&31)] = f2bf(W1[i]);
}

// ---- [256][64] fp32 weight -> bf16, layout [kc][col][kk] ----
__global__ void k_prep_w64(const float* __restrict__ W, ushort* __restrict__ Wh){
  int i = blockIdx.x*256 + threadIdx.x;   // i = k*64 + col, 16384 total
  int k = i >> 6, col = i & 63;
  Wh[(k>>5)*2048 + col*32 + (k&31)] = f2bf(W[i]);
}

// ---------------- GEMM1 (MFMA, bf16) + bias + relu + LN -> ego(bf16) ----
__global__ __launch_bounds__(256) void k_gemm1_mfma(const float* __restrict__ x,
    const ushort* __restrict__ W1s, const float* __restrict__ b1,
    const float* __restrict__ g, const float* __restrict__ bb,
    ushort* __restrict__ ego, int N){
  __shared__ ushort xh[64][40];
  __shared__ ushort wl[256][40];
  __shared__ float psum[64][4], psq[64][4];
  __shared__ float mub[64], ivb[64];

  const int tid = threadIdx.x;
  const int n0  = blockIdx.x*64;
  const int w   = tid>>6;
  const int l   = tid&63;
  const int l15 = l&15;
  const int lg  = l>>4;            // 0..3
  const int cb  = w*64;            // wave col base
  const int sxr = tid>>2;          // x row 0..63
  const int sxk = (tid&3)*8;       // k offset {0,8,16,24}

  f32x4 acc[4][4];
  #pragma unroll
  for (int rt=0;rt<4;rt++)
    #pragma unroll
    for (int ct=0;ct<4;ct++)
      acc[rt][ct] = (f32x4){0.f,0.f,0.f,0.f};

  for (int kc=0; kc<8; ++kc){
    if (kc) __syncthreads();
    const float* xp = &x[(size_t)min(n0+sxr, N-1)*256 + kc*32 + sxk];
    float4 v0 = *reinterpret_cast<const float4*>(xp);
    float4 v1 = *reinterpret_cast<const float4*>(xp+4);
    const float vv[8] = {v0.x,v0.y,v0.z,v0.w,v1.x,v1.y,v1.z,v1.w};
    bf16x8 hv;
    #pragma unroll
    for (int j=0;j<8;j++) hv[j] = (short)f2bf(vv[j]);
    *reinterpret_cast<bf16x8*>(&xh[sxr][sxk]) = hv;
    #pragma unroll
    for (int s2=0;s2<4;s2++){
      int rowi = (tid>>2) + s2*64;
      *reinterpret_cast<bf16x8*>(&wl[rowi][(tid&3)*8]) =
          *reinterpret_cast<const bf16x8*>(&W1s[kc*8192 + rowi*32 + (tid&3)*8]);
    }
    __syncthreads();
    bf16x8 ah[4];
    #pragma unroll
    for (int rt=0;rt<4;rt++)
      ah[rt] = *reinterpret_cast<const bf16x8*>(&xh[rt*16+l15][lg*8]);
    #pragma unroll
    for (int ct=0;ct<4;ct++){
      bf16x8 bv = *reinterpret_cast<const bf16x8*>(&wl[cb+ct*16+l15][lg*8]);
      #pragma unroll
      for (int rt=0;rt<4;rt++)
        acc[rt][ct] = __builtin_amdgcn_mfma_f32_16x16x32_bf16(ah[rt], bv, acc[rt][ct], 0,0,0);
    }
  }

  float b1v[4], gv[4], bbv[4];
  #pragma unroll
  for (int ct=0;ct<4;ct++){
    int col = cb + ct*16 + l15;
    b1v[ct] = b1[col]; gv[ct] = g[col]; bbv[ct] = bb[col];
  }
  #pragma unroll
  for (int rt=0;rt<4;rt++)
    #pragma unroll
    for (int ct=0;ct<4;ct++)
      #pragma unroll
      for (int r=0;r<4;r++)
        acc[rt][ct][r] = fmaxf(acc[rt][ct][r] + b1v[ct], 0.f);

  #pragma unroll
  for (int rt=0;rt<4;rt++){
    #pragma unroll
    for (int r=0;r<4;r++){
      float s = acc[rt][0][r]+acc[rt][1][r]+acc[rt][2][r]+acc[rt][3][r];
      float q = acc[rt][0][r]*acc[rt][0][r]+acc[rt][1][r]*acc[rt][1][r]
              + acc[rt][2][r]*acc[rt][2][r]+acc[rt][3][r]*acc[rt][3][r];
      #pragma unroll
      for (int o=1;o<16;o<<=1){ s += __shfl_xor(s,o); q += __shfl_xor(q,o); }
      if (l15 == 0){
        int row = rt*16 + lg*4 + r;
        psum[row][w] = s; psq[row][w] = q;
      }
    }
  }
  __syncthreads();
  if (tid < 64){
    float s = psum[tid][0]+psum[tid][1]+psum[tid][2]+psum[tid][3];
    float q = psq[tid][0]+psq[tid][1]+psq[tid][2]+psq[tid][3];
    float mu  = s * (1.f/256.f);
    float var = q * (1.f/256.f) - mu*mu;
    mub[tid] = mu;
    ivb[tid] = rsqrtf(fmaxf(var, 0.f) + kEps);
  }
  __syncthreads();
  #pragma unroll
  for (int rt=0;rt<4;rt++){
    #pragma unroll
    for (int r=0;r<4;r++){
      int row  = rt*16 + lg*4 + r;
      int grow = n0 + row;
      if (grow < N){
        float mu = mub[row], inv = ivb[row];
        size_t base = (size_t)grow*256 + cb + l15;
        #pragma unroll
        for (int ct=0;ct<4;ct++)
          ego[base + ct*16] = f2bf((acc[rt][ct][r]-mu)*inv*gv[ct] + bbv[ct]);
      }
    }
  }
}

// ------- MFMA 256->64 GEMM (bf16 x, bf16 W) -> bf16 h -------
__global__ __launch_bounds__(256) void k_hgemm_mfma(const ushort* __restrict__ x,
    const ushort* __restrict__ Wh, ushort* __restrict__ h, int N){
  __shared__ ushort xs[64][40];
  __shared__ ushort wh[64][40];
  const int tid = threadIdx.x;
  const int n0  = blockIdx.x*64;
  const int w   = tid>>6;
  const int l15 = tid&15;
  const int lg  = (tid&63)>>4;
  const int sxr = tid>>2;
  const int sxk = (tid&3)*8;

  f32x4 acc[4];
  #pragma unroll
  for (int ct=0;ct<4;ct++) acc[ct] = (f32x4){0.f,0.f,0.f,0.f};

  for (int kc=0; kc<8; ++kc){
    if (kc) __syncthreads();
    *reinterpret_cast<bf16x8*>(&xs[sxr][sxk]) =
        *reinterpret_cast<const bf16x8*>(&x[(size_t)min(n0+sxr, N-1)*256 + kc*32 + sxk]);
    int src = kc*2048 + sxr*32 + sxk;
    *reinterpret_cast<bf16x8*>(&wh[sxr][sxk]) =
        *reinterpret_cast<const bf16x8*>(&Wh[src]);
    __syncthreads();
    bf16x8 ah = *reinterpret_cast<const bf16x8*>(&xs[w*16+l15][lg*8]);
    #pragma unroll
    for (int ct=0;ct<4;ct++){
      bf16x8 bh = *reinterpret_cast<const bf16x8*>(&wh[ct*16+l15][lg*8]);
      acc[ct] = __builtin_amdgcn_mfma_f32_16x16x32_bf16(ah, bh, acc[ct], 0,0,0);
    }
  }
  #pragma unroll
  for (int r=0;r<4;r++){
    int grow = n0 + w*16 + lg*4 + r;
    if (grow < N){
      #pragma unroll
      for (int ct=0;ct<4;ct++)
        h[(size_t)grow*64 + ct*16 + l15] = f2bf(acc[ct][r]);
    }
  }
}

// ------- MFMA 256->64 GEMM + bias + log_softmax -> out -------
__global__ __launch_bounds__(256) void k_out_mfma(const ushort* __restrict__ x,
    const ushort* __restrict__ Wh, const float* __restrict__ b2,
    float* __restrict__ out, int N){
  __shared__ ushort xs[64][40];
  __shared__ ushort wh[64][40];
  const int tid = threadIdx.x;
  const int n0  = blockIdx.x*64;
  const int w   = tid>>6;
  const int l15 = tid&15;
  const int lg  = (tid&63)>>4;
  const int sxr = tid>>2;
  const int sxk = (tid&3)*8;

  f32x4 acc[4];
  #pragma unroll
  for (int ct=0;ct<4;ct++) acc[ct] = (f32x4){0.f,0.f,0.f,0.f};

  for (int kc=0; kc<8; ++kc){
    if (kc) __syncthreads();
    *reinterpret_cast<bf16x8*>(&xs[sxr][sxk]) =
        *reinterpret_cast<const bf16x8*>(&x[(size_t)min(n0+sxr, N-1)*256 + kc*32 + sxk]);
    int src = kc*2048 + sxr*32 + sxk;
    *reinterpret_cast<bf16x8*>(&wh[sxr][sxk]) =
        *reinterpret_cast<const bf16x8*>(&Wh[src]);
    __syncthreads();
    bf16x8 ah = *reinterpret_cast<const bf16x8*>(&xs[w*16+l15][lg*8]);
    #pragma unroll
    for (int ct=0;ct<4;ct++){
      bf16x8 bh = *reinterpret_cast<const bf16x8*>(&wh[ct*16+l15][lg*8]);
      acc[ct] = __builtin_amdgcn_mfma_f32_16x16x32_bf16(ah, bh, acc[ct], 0,0,0);
    }
  }

  float b2v[4];
  #pragma unroll
  for (int ct=0;ct<4;ct++) b2v[ct] = b2[ct*16+l15];

  #pragma unroll
  for (int r=0;r<4;r++){
    float v[4];
    #pragma unroll
    for (int ct=0;ct<4;ct++) v[ct] = acc[ct][r] + b2v[ct];
    float mx = fmaxf(fmaxf(v[0],v[1]), fmaxf(v[2],v[3]));
    #pragma unroll
    for (int o=1;o<16;o<<=1) mx = fmaxf(mx, __shfl_xor(mx,o));
    float sm = __expf(v[0]-mx)+__expf(v[1]-mx)+__expf(v[2]-mx)+__expf(v[3]-mx);
    #pragma unroll
    for (int o=1;o<16;o<<=1) sm += __shfl_xor(sm,o);
    float ls = __logf(sm);
    int grow = n0 + w*16 + lg*4 + r;
    if (grow < N){
      #pragma unroll
      for (int ct=0;ct<4;ct++)
        out[(size_t)grow*64 + ct*16 + l15] = (v[ct]-mx) - ls;
    }
  }
}

// ------- FUSED edge phase, 1-wave blocks, LDS-staged h[row] -------
__global__ __launch_bounds__(64) void k_att_agg(
    const ushort* __restrict__ h,      // [N][64] bf16
    const int* __restrict__ colcsr, const int* __restrict__ start,
    const float* __restrict__ attw,    // [64][4]
    const ushort* __restrict__ ego,    // [N][256] bf16
    const float* __restrict__ g, const float* __restrict__ b,
    ushort* __restrict__ xout, int N){
  __shared__ ushort s_hr[4][72];
  __shared__ ushort s_hc[64][72];
  __shared__ float4 s_a[64];

  const int lane = threadIdx.x;        // 0..63
  const int grp  = lane >> 4;
  const int l15  = lane & 15;
  const int nb   = blockIdx.x*4;
  const int n    = nb + grp;           // group's node

  const int b0  = start[nb];
  const int st1 = start[min(nb+1, N)];
  const int st2 = start[min(nb+2, N)];
  const int st3 = start[min(nb+3, N)];
  const int b1  = start[min(nb+4, N)];
  const int s0 = (n < N) ? start[n]   : b1;
  const int s1 = (n < N) ? start[n+1] : b1;

  *reinterpret_cast<ushort4*>(&s_hr[grp][l15*4]) =
      *reinterpret_cast<const ushort4*>(&h[(size_t)min(n, N-1)*64 + l15*4]);

  float acc[4][4];
  #pragma unroll
  for (int c=0;c<4;c++)
    #pragma unroll
    for (int j=0;j<4;j++) acc[c][j]=0.f;

  for (int base = b0; base < b1; base += 64){
    const int cnt = min(b1 - base, 64);
    if (lane < cnt){
      int edge = base + lane;
      int rl = (edge >= st2) ? ((edge >= st3) ? 3 : 2)
                             : ((edge >= st1) ? 1 : 0);
      int c = colcsr[edge];
      const uint4* hrp = reinterpret_cast<const uint4*>(&s_hr[rl][0]);
      const uint4* hcp = reinterpret_cast<const uint4*>(h + (size_t)c*64);
      float q0=0.f, q1=0.f, q2=0.f, q3=0.f;
      #pragma unroll
      for (int s=0; s<8; ++s){
        uint4 hr4 = hrp[s];
        uint4 hc4 = hcp[s];
        *reinterpret_cast<uint4*>(&s_hc[lane][s*8]) = hc4;
        const uint hru[4] = {hr4.x, hr4.y, hr4.z, hr4.w};
        const uint hcu[4] = {hc4.x, hc4.y, hc4.z, hc4.w};
        #pragma unroll
        for (int t=0; t<4; ++t){
          float hrl = __uint_as_float(hru[t]<<16);
          float hrh = __uint_as_float(hru[t]&0xffff0000u);
          float hcl = __uint_as_float(hcu[t]<<16);
          float hch = __uint_as_float(hcu[t]&0xffff0000u);
          float pl = fmaxf(fmaf(0.5f, hrl, hcl), 0.f);
          float ph = fmaxf(fmaf(0.5f, hrh, hch), 0.f);
          int d = s*8 + t*2;
          float4 w0 = *reinterpret_cast<const float4*>(&attw[(d  )*4]);
          float4 w1 = *reinterpret_cast<const float4*>(&attw[(d+1)*4]);
          q0 = fmaf(pl, w0.x, q0); q1 = fmaf(pl, w0.y, q1);
          q2 = fmaf(pl, w0.z, q2); q3 = fmaf(pl, w0.w, q3);
          q0 = fmaf(ph, w1.x, q0); q1 = fmaf(ph, w1.y, q1);
          q2 = fmaf(ph, w1.z, q2); q3 = fmaf(ph, w1.w, q3);
        }
      }
      float m = fmaxf(fmaxf(q0,q1), fmaxf(q2,q3));
      float e0=__expf(q0-m), e1=__expf(q1-m), e2=__expf(q2-m), e3=__expf(q3-m);
      float inv = 1.f/(e0+e1+e2+e3);
      s_a[lane] = make_float4(e0*inv, e1*inv, e2*inv, e3*inv);
    }
    __syncthreads();
    int lo = max(s0, base), hi = min(s1, base + cnt);
    for (int i = lo; i < hi; ++i){
      int e = i - base;
      float4 av = s_a[e];
      ushort4 hv = *reinterpret_cast<const ushort4*>(&s_hc[e][l15*4]);
      float d0=bf2f(hv.x), d1=bf2f(hv.y), d2=bf2f(hv.z), d3=bf2f(hv.w);
      acc[0][0]=fmaf(av.x,d0,acc[0][0]); acc[0][1]=fmaf(av.x,d1,acc[0][1]);
      acc[0][2]=fmaf(av.x,d2,acc[0][2]); acc[0][3]=fmaf(av.x,d3,acc[0][3]);
      acc[1][0]=fmaf(av.y,d0,acc[1][0]); acc[1][1]=fmaf(av.y,d1,acc[1][1]);
      acc[1][2]=fmaf(av.y,d2,acc[1][2]); acc[1][3]=fmaf(av.y,d3,acc[1][3]);
      acc[2][0]=fmaf(av.z,d0,acc[2][0]); acc[2][1]=fmaf(av.z,d1,acc[2][1]);
      acc[2][2]=fmaf(av.z,d2,acc[2][2]); acc[2][3]=fmaf(av.z,d3,acc[2][3]);
      acc[3][0]=fmaf(av.w,d0,acc[3][0]); acc[3][1]=fmaf(av.w,d1,acc[3][1]);
      acc[3][2]=fmaf(av.w,d2,acc[3][2]); acc[3][3]=fmaf(av.w,d3,acc[3][3]);
    }
    if (base + 64 < b1) __syncthreads();
  }

  if (n >= N) return;

  #pragma unroll
  for (int c=0;c<4;c++)
    #pragma unroll
    for (int j=0;j<4;j++)
      acc[c][j] = fmaxf(acc[c][j], 0.f);

  float s=0.f, sq=0.f;
  #pragma unroll
  for (int c=0;c<4;c++)
    #pragma unroll
    for (int j=0;j<4;j++){ float v=acc[c][j]; s+=v; sq+=v*v; }
  #pragma unroll
  for (int o=1;o<16;o<<=1){ s += __shfl_xor(s,o); sq += __shfl_xor(sq,o); }
  float mu  = s * (1.f/256.f);
  float var = sq * (1.f/256.f) - mu*mu;
  float inv = rsqrtf(fmaxf(var,0.f) + kEps);

  size_t nbase = (size_t)n*256;
  #pragma unroll
  for (int c=0;c<4;c++){
    int colb = c*64 + l15*4;
    float4 gv  = *reinterpret_cast<const float4*>(&g[colb]);
    float4 bv  = *reinterpret_cast<const float4*>(&b[colb]);
    ushort4 ev = *reinterpret_cast<const ushort4*>(&ego[nbase + colb]);
    ushort4 y;
    y.x = f2bf((1.f-kBeta)*((acc[c][0]-mu)*inv*gv.x + bv.x) + kBeta*bf2f(ev.x));
    y.y = f2bf((1.f-kBeta)*((acc[c][1]-mu)*inv*gv.y + bv.y) + kBeta*bf2f(ev.y));
    y.z = f2bf((1.f-kBeta)*((acc[c][2]-mu)*inv*gv.z + bv.z) + kBeta*bf2f(ev.z));
    y.w = f2bf((1.f-kBeta)*((acc[c][3]-mu)*inv*gv.w + bv.w) + kBeta*bf2f(ev.w));
    *reinterpret_cast<ushort4*>(&xout[nbase + colb]) = y;
  }
}

extern "C" void kernel_launch(void* const* d_in, const int* in_sizes, int n_in,
                              void* d_out, int out_size, void* d_ws, size_t ws_size,
                              hipStream_t stream){
  const float* x_in = (const float*)d_in[0];
  const int*   ei   = (const int*)d_in[1];
  const float* W1   = (const float*)d_in[2];
  const float* b1   = (const float*)d_in[3];
  const float* lin  = (const float*)d_in[4];
  const float* att  = (const float*)d_in[5];
  const float* lng  = (const float*)d_in[6];
  const float* lnb  = (const float*)d_in[7];
  const float* W2   = (const float*)d_in[8];
  const float* b2   = (const float*)d_in[9];
  float* out = (float*)d_out;

  const int N = in_sizes[0] / 256;   // 50000
  const int E = in_sizes[1] / 2;     // 800000
  const int* row = ei;
  const int* col = ei + E;

  char* basep = (char*)d_ws;
  size_t off = 0;
  auto alloc = [&](size_t bytes)->char*{
    char* p = basep + off;
    off += (bytes + 255) & ~(size_t)255;
    return p;
  };
  ushort* ego    = (ushort*)alloc((size_t)N*256*2);
  ushort* xbuf   = (ushort*)alloc((size_t)N*256*2);
  ushort* hbuf   = (ushort*)alloc((size_t)N*64*2);
  int*    startp = (int*)   alloc((size_t)(N+1)*4);
  int*    deg    = (int*)   alloc((size_t)N*4);   // also reused as cursor
  int*    colcsr = (int*)   alloc((size_t)E*4);
  int*    bsum   = (int*)   alloc(256*4);
  int*    boff   = (int*)   alloc(256*4);
  ushort* W1s    = (ushort*)alloc((size_t)256*256*2);
  ushort* linh   = (ushort*)alloc((size_t)2*16384*2);
  ushort* W2h    = (ushort*)alloc((size_t)16384*2);

  int nbE = (E + 255)/256;   // 3125
  int nbN = (N + 255)/256;   // 196
  int nbT = (N + 63)/64;     // 782 tiles
  int NR4 = (N + 3)/4;       // node range per 4-class bin

  // CSR build (simple hist, 4-class binned fill)
  hipMemsetAsync(deg, 0, (size_t)N*4, stream);
  k_hist<<<nbE,256,0,stream>>>(row, deg, E);
  k_scan_block<<<nbN,256,0,stream>>>(deg, startp, bsum, N);
  k_scan_bsum<<<1,256,0,stream>>>(bsum, boff, nbN);
  k_scan_add<<<nbN,256,0,stream>>>(startp, boff, N);
  hipMemsetAsync(deg, 0, (size_t)N*4, stream);     // cursor
  k_fill_bin<<<1024,256,0,stream>>>(row, col, startp, deg, colcsr, E, NR4);

  // weight prep
  k_prep_w1<<<256,256,0,stream>>>(W1, W1s);
  k_prep_w64<<<64,256,0,stream>>>(lin,          linh);
  k_prep_w64<<<64,256,0,stream>>>(lin + 16384,  linh + 16384);
  k_prep_w64<<<64,256,0,stream>>>(W2, W2h);

  // MFMA projection + bias + relu + LN -> ego (bf16)
  k_gemm1_mfma<<<nbT,256,0,stream>>>(x_in, W1s, b1, lng, lnb, ego, N);

  for (int L=0; L<2; ++L){
    const ushort* xsrc = (L == 0) ? ego : xbuf;
    k_hgemm_mfma<<<nbT,256,0,stream>>>(xsrc, linh + (size_t)L*16384, hbuf, N);
    k_att_agg<<<(N+3)/4,64,0,stream>>>(hbuf, colcsr, startp,
                                       att + (size_t)L*64*4, ego,
                                       lng + (size_t)(L+1)*256, lnb + (size_t)(L+1)*256,
                                       xbuf, N);
  }
  k_out_mfma<<<nbT,256,0,stream>>>(xbuf, W2h, b2, out, N);
}